// Round 1
// baseline (389.901 us; speedup 1.0000x reference)
//
#include <hip/hip_runtime.h>
#include <hip/hip_bf16.h>

#define BATCH 8192
#define IN_DIM 784
#define HID 128
#define CLS 10
#define ENSEMBLE 16
#define INTERNAL 255
#define TOTAL 511
#define KPAD 800  // 784 padded up to multiple of 32 for MFMA K-steps

typedef __attribute__((ext_vector_type(8))) short short8;   // 8 bf16 = 4 VGPRs (MFMA A/B frag)
typedef __attribute__((ext_vector_type(4))) float floatx4;  // MFMA C/D frag

// ---- workspace layout (bytes) ----
// feats_f32: BATCH*HID*4      = 4194304   @ 0
// feats_bf : BATCH*HID*2      = 2097152   @ 4194304
// Xbf      : BATCH*KPAD*2     = 13107200  @ 6291456
// W1T_bf   : HID*KPAD*2       = 204800    @ 19398656
// nodeWbf  : ENSEMBLE*256*HID*2 = 1048576 @ 19603456
// total ~20.7 MB

// K0: fp32 -> bf16 conversions (with zero padding in K and node dims)
__global__ void convert_kernel(const float* __restrict__ X,
                               const float* __restrict__ W1,
                               const float* __restrict__ nodeW,
                               __hip_bfloat16* __restrict__ Xbf,
                               __hip_bfloat16* __restrict__ W1T,
                               __hip_bfloat16* __restrict__ nWbf) {
  const int N1 = BATCH * KPAD;
  const int N2 = HID * KPAD;
  const int N3 = ENSEMBLE * 256 * HID;
  const int total = N1 + N2 + N3;
  for (int i = blockIdx.x * blockDim.x + threadIdx.x; i < total;
       i += gridDim.x * blockDim.x) {
    if (i < N1) {
      int b = i / KPAD, k = i - b * KPAD;
      float v = (k < IN_DIM) ? X[b * IN_DIM + k] : 0.0f;
      Xbf[i] = __float2bfloat16(v);
    } else if (i < N1 + N2) {
      int j = i - N1;
      int c = j / KPAD, k = j - c * KPAD;
      float v = (k < IN_DIM) ? W1[k * HID + c] : 0.0f;  // transpose: W1T[c][k]
      W1T[j] = __float2bfloat16(v);
    } else {
      int j = i - N1 - N2;
      int t = j / (256 * HID);
      int r = j - t * 256 * HID;
      int ii = r / HID;
      int d = r - ii * HID;
      float v = (ii < INTERNAL) ? nodeW[(t * INTERNAL + ii) * HID + d] : 0.0f;
      nWbf[j] = __float2bfloat16(v);
    }
  }
}

// K1: feats = relu(X @ W1 + b1), bf16 MFMA, K=800 (padded).
// Block = 128 threads (2 waves); each wave does one 16-row m-tile x all 8 n-tiles.
__global__ __launch_bounds__(128) void feats_kernel(
    const __hip_bfloat16* __restrict__ Xbf,
    const __hip_bfloat16* __restrict__ W1T,
    const float* __restrict__ b1,
    float* __restrict__ feats,
    __hip_bfloat16* __restrict__ featsbf) {
  const int wave = threadIdx.x >> 6;
  const int lane = threadIdx.x & 63;
  const int lo = lane & 15;
  const int q = lane >> 4;
  const int m0 = blockIdx.x * 32 + wave * 16;

  floatx4 acc[8];
#pragma unroll
  for (int nt = 0; nt < 8; nt++) acc[nt] = (floatx4){0.f, 0.f, 0.f, 0.f};

  const short* Xp = (const short*)Xbf;
  const short* Wp = (const short*)W1T;
  for (int ks = 0; ks < KPAD / 32; ks++) {
    const int koff = ks * 32 + q * 8;
    // A frag: A[m=lo][k=q*8+j], contiguous in k
    short8 a = *(const short8*)(Xp + (size_t)(m0 + lo) * KPAD + koff);
#pragma unroll
    for (int nt = 0; nt < 8; nt++) {
      // B frag: B[k=q*8+j][n=lo] = W1T[n][k], contiguous in k
      short8 b = *(const short8*)(Wp + (size_t)(nt * 16 + lo) * KPAD + koff);
      acc[nt] = __builtin_amdgcn_mfma_f32_16x16x32_bf16(a, b, acc[nt], 0, 0, 0);
    }
  }
#pragma unroll
  for (int nt = 0; nt < 8; nt++) {
    const int c = nt * 16 + lo;  // D col = lane&15
    const float bias = b1[c];
#pragma unroll
    for (int r = 0; r < 4; r++) {
      const int brow = m0 + q * 4 + r;  // D row = quad*4 + reg
      float v = acc[nt][r] + bias;
      v = fmaxf(v, 0.0f);
      feats[(size_t)brow * HID + c] = v;
      featsbf[(size_t)brow * HID + c] = __float2bfloat16(v);
    }
  }
}

// K2: prediction = feats @ W2 + b2 (8192x10, K=128). Tiny; fp32.
__global__ void pred_kernel(const float* __restrict__ feats,
                            const float* __restrict__ W2,
                            const float* __restrict__ b2,
                            float* __restrict__ out) {
  int gid = blockIdx.x * blockDim.x + threadIdx.x;
  if (gid >= BATCH * CLS) return;
  int b = gid / CLS, c = gid - b * CLS;
  float acc = b2[c];
  const float* fr = feats + (size_t)b * HID;
#pragma unroll 4
  for (int k = 0; k < HID; k++) acc += fr[k] * W2[k * CLS + c];
  out[gid] = acc;
}

// K3: fused dec-GEMM (bf16 MFMA) + sigmoid + tree path products.
// Block = 256 threads (4 waves). One block = (tree t, 32-batch tile).
// GEMM: M=256 node rows (255 real), N=32 batch cols, K=128.
// Fragments loaded straight from global (16B/lane contiguous, L2-hot).
__global__ __launch_bounds__(256) void tree_kernel(
    const __hip_bfloat16* __restrict__ featsbf,
    const __hip_bfloat16* __restrict__ nWbf,
    const float* __restrict__ nodeb,
    float* __restrict__ out /* all_results base, [16][511][8192] */) {
  __shared__ float dec_s[INTERNAL * 32];  // sigmoid decisions, heap-indexed
  __shared__ float P_s[INTERNAL * 32];    // internal-node path products, heap-indexed

  const int t = blockIdx.y;
  const int b0 = blockIdx.x * 32;
  const int tid = threadIdx.x;
  const int wave = tid >> 6;
  const int lane = tid & 63;
  const int lo = lane & 15;
  const int q = lane >> 4;

  const short* Fp = (const short*)featsbf;
  const short* Np = (const short*)nWbf;

  // B frags (feats tile): 2 n-tiles x 4 k-steps, reused across all m-tiles
  short8 bfr[2][4];
#pragma unroll
  for (int nt = 0; nt < 2; nt++)
#pragma unroll
    for (int ks = 0; ks < 4; ks++)
      bfr[nt][ks] =
          *(const short8*)(Fp + (size_t)(b0 + nt * 16 + lo) * HID + ks * 32 + q * 8);

#pragma unroll
  for (int mt = 0; mt < 4; mt++) {
    const int ibase = wave * 64 + mt * 16;
    floatx4 acc0 = {0.f, 0.f, 0.f, 0.f};
    floatx4 acc1 = {0.f, 0.f, 0.f, 0.f};
#pragma unroll
    for (int ks = 0; ks < 4; ks++) {
      short8 a = *(const short8*)(Np + (size_t)(t * 256 + ibase + lo) * HID +
                                  ks * 32 + q * 8);
      acc0 = __builtin_amdgcn_mfma_f32_16x16x32_bf16(a, bfr[0][ks], acc0, 0, 0, 0);
      acc1 = __builtin_amdgcn_mfma_f32_16x16x32_bf16(a, bfr[1][ks], acc1, 0, 0, 0);
    }
#pragma unroll
    for (int r = 0; r < 4; r++) {
      const int iloc = ibase + q * 4 + r;  // D row
      if (iloc < INTERNAL) {
        const float nb = nodeb[t * INTERNAL + iloc];
        const float x0 = acc0[r] + nb;
        const float x1 = acc1[r] + nb;
        dec_s[iloc * 32 + lo] = 1.0f / (1.0f + __expf(-x0));
        dec_s[iloc * 32 + 16 + lo] = 1.0f / (1.0f + __expf(-x1));
      }
    }
  }
  __syncthreads();

  float* outT = out + (size_t)t * TOTAL * BATCH + b0;
  // root node value = 1
  if (tid < 32) {
    P_s[tid] = 1.0f;
    outT[tid] = 1.0f;
  }
  __syncthreads();

  // level-by-level: parents at heap [start, start+cnt), children at [2*start+1, ...)
  for (int lvl = 0; lvl < 8; lvl++) {
    const int start = (1 << lvl) - 1;
    const int nchild = 2 << lvl;
    const int items = nchild * 32;
    for (int it = tid; it < items; it += 256) {
      const int c = it >> 5;
      const int b = it & 31;
      const int pnode = start + (c >> 1);
      const float d = dec_s[pnode * 32 + b];
      const float pv = P_s[pnode * 32 + b];
      const float val = pv * ((c & 1) ? (1.0f - d) : d);  // left=*d, right=*(1-d)
      const int cnode = 2 * start + 1 + c;
      outT[(size_t)cnode * BATCH + b] = val;
      if (cnode < INTERNAL) P_s[cnode * 32 + b] = val;
    }
    __syncthreads();
  }
}

extern "C" void kernel_launch(void* const* d_in, const int* in_sizes, int n_in,
                              void* d_out, int out_size, void* d_ws, size_t ws_size,
                              hipStream_t stream) {
  const float* X = (const float*)d_in[0];
  const float* W1 = (const float*)d_in[1];
  const float* b1 = (const float*)d_in[2];
  const float* W2 = (const float*)d_in[3];
  const float* b2 = (const float*)d_in[4];
  const float* nodeW = (const float*)d_in[5];
  const float* nodeb = (const float*)d_in[6];

  float* pred_out = (float*)d_out;
  float* results_out = pred_out + BATCH * CLS;

  char* ws = (char*)d_ws;
  float* feats = (float*)(ws + 0);
  __hip_bfloat16* featsbf = (__hip_bfloat16*)(ws + 4194304);
  __hip_bfloat16* Xbf = (__hip_bfloat16*)(ws + 6291456);
  __hip_bfloat16* W1T = (__hip_bfloat16*)(ws + 19398656);
  __hip_bfloat16* nWbf = (__hip_bfloat16*)(ws + 19603456);

  convert_kernel<<<2048, 256, 0, stream>>>(X, W1, nodeW, Xbf, W1T, nWbf);
  feats_kernel<<<BATCH / 32, 128, 0, stream>>>(Xbf, W1T, b1, feats, featsbf);
  pred_kernel<<<(BATCH * CLS + 255) / 256, 256, 0, stream>>>(feats, W2, b2, pred_out);
  tree_kernel<<<dim3(BATCH / 32, ENSEMBLE), 256, 0, stream>>>(featsbf, nWbf, nodeb,
                                                              results_out);
}

// Round 2
// 343.603 us; speedup vs baseline: 1.1347x; 1.1347x over previous
//
#include <hip/hip_runtime.h>
#include <hip/hip_bf16.h>

#define BATCH 8192
#define IN_DIM 784
#define HID 128
#define CLS 10
#define ENSEMBLE 16
#define INTERNAL 255
#define TOTAL 511
#define KPAD 800  // 784 padded to multiple of 32 for MFMA K-steps

typedef __attribute__((ext_vector_type(8))) short short8;   // 8 bf16 (MFMA A/B frag)
typedef __attribute__((ext_vector_type(4))) float floatx4;  // MFMA C/D frag

// ---- workspace layout (bytes) ----
// W1T_bf  : HID*KPAD*2        = 204800   @ 0
// nodeWbf : ENSEMBLE*256*HID*2= 1048576  @ 204800
// featsbf : BATCH*HID*2       = 2097152  @ 1253376
// total ~3.2 MB

__device__ inline short f2bf(float f) {
  __hip_bfloat16 h = __float2bfloat16(f);
  return *reinterpret_cast<short*>(&h);
}

// K0: small fp32 -> bf16 conversions (W1 transpose+pad, nodeW pad)
__global__ void convert_kernel(const float* __restrict__ W1,
                               const float* __restrict__ nodeW,
                               __hip_bfloat16* __restrict__ W1T,
                               __hip_bfloat16* __restrict__ nWbf) {
  const int N2 = HID * KPAD;              // 102400
  const int N3 = ENSEMBLE * 256 * HID;    // 524288
  const int total = N2 + N3;
  for (int i = blockIdx.x * blockDim.x + threadIdx.x; i < total;
       i += gridDim.x * blockDim.x) {
    if (i < N2) {
      int c = i / KPAD, k = i - c * KPAD;
      float v = (k < IN_DIM) ? W1[k * HID + c] : 0.0f;  // W1T[c][k]
      W1T[i] = __float2bfloat16(v);
    } else {
      int j = i - N2;
      int t = j >> 15;            // /(256*HID)
      int r = j & 32767;
      int ii = r >> 7;            // /HID
      int d = r & 127;
      float v = (ii < INTERNAL) ? nodeW[(t * INTERNAL + ii) * HID + d] : 0.0f;
      nWbf[j] = __float2bfloat16(v);
    }
  }
}

// K1: featsbf = relu(X @ W1 + b1) in bf16. X read fp32 and converted in-register.
// Block = 256 (4 waves). Block owns one 16-row m-tile; wave w owns cols [w*32, w*32+32).
// Grid = 512 blocks -> 2 blocks/CU, 8 waves/CU.
__global__ __launch_bounds__(256) void feats_kernel(
    const float* __restrict__ X,
    const __hip_bfloat16* __restrict__ W1T,
    const float* __restrict__ b1,
    __hip_bfloat16* __restrict__ featsbf) {
  const int wave = threadIdx.x >> 6;
  const int lane = threadIdx.x & 63;
  const int lo = lane & 15;
  const int q = lane >> 4;
  const int m0 = blockIdx.x * 16;
  const int cb = wave * 32;

  floatx4 acc0 = {0.f, 0.f, 0.f, 0.f};
  floatx4 acc1 = {0.f, 0.f, 0.f, 0.f};
  const short* Wp = (const short*)W1T;
  const float* Xrow = X + (size_t)(m0 + lo) * IN_DIM;

  for (int ks = 0; ks < KPAD / 32; ks++) {
    const int k0 = ks * 32 + q * 8;
    short8 a;
    if (k0 + 8 <= IN_DIM) {
      float4 x0 = *(const float4*)(Xrow + k0);
      float4 x1 = *(const float4*)(Xrow + k0 + 4);
      a[0] = f2bf(x0.x); a[1] = f2bf(x0.y); a[2] = f2bf(x0.z); a[3] = f2bf(x0.w);
      a[4] = f2bf(x1.x); a[5] = f2bf(x1.y); a[6] = f2bf(x1.z); a[7] = f2bf(x1.w);
    } else {
      a = (short8){0, 0, 0, 0, 0, 0, 0, 0};
    }
    short8 b0f = *(const short8*)(Wp + (size_t)(cb + lo) * KPAD + k0);
    short8 b1f = *(const short8*)(Wp + (size_t)(cb + 16 + lo) * KPAD + k0);
    acc0 = __builtin_amdgcn_mfma_f32_16x16x32_bf16(a, b0f, acc0, 0, 0, 0);
    acc1 = __builtin_amdgcn_mfma_f32_16x16x32_bf16(a, b1f, acc1, 0, 0, 0);
  }
#pragma unroll
  for (int nt = 0; nt < 2; nt++) {
    const floatx4 acc = nt ? acc1 : acc0;
    const int c = cb + nt * 16 + lo;   // D col = lane&15
    const float bias = b1[c];
#pragma unroll
    for (int r = 0; r < 4; r++) {
      const int row = m0 + q * 4 + r;  // D row = quad*4 + reg
      float v = fmaxf(acc[r] + bias, 0.0f);
      featsbf[(size_t)row * HID + c] = __float2bfloat16(v);
    }
  }
}

// K2: prediction = feats @ W2 + b2 (8192x10, K=128), bf16 feats, W2 in LDS.
__global__ __launch_bounds__(256) void pred_kernel(
    const __hip_bfloat16* __restrict__ featsbf,
    const float* __restrict__ W2,
    const float* __restrict__ b2,
    float* __restrict__ out) {
  __shared__ float W2s[HID * CLS];
  __shared__ float b2s[CLS];
  for (int i = threadIdx.x; i < HID * CLS; i += 256) W2s[i] = W2[i];
  if (threadIdx.x < CLS) b2s[threadIdx.x] = b2[threadIdx.x];
  __syncthreads();
  int gid = blockIdx.x * 256 + threadIdx.x;
  if (gid >= BATCH * CLS) return;
  int b = gid / CLS, c = gid - b * CLS;
  const short* fr = (const short*)featsbf + (size_t)b * HID;
  float acc = b2s[c];
#pragma unroll
  for (int kk = 0; kk < HID / 8; kk++) {
    short8 f8 = *(const short8*)(fr + kk * 8);
#pragma unroll
    for (int j = 0; j < 8; j++) {
      unsigned u = ((unsigned)(unsigned short)f8[j]) << 16;  // exact bf16->f32
      acc += __uint_as_float(u) * W2s[(kk * 8 + j) * CLS + c];
    }
  }
  out[gid] = acc;
}

// K3: fused dec-GEMM (bf16 MFMA) + sigmoid + tree path products.
// Block = 256 threads (4 waves) = (tree t, 32-batch tile). LDS = dec only (32.6 KB)
// -> 4 blocks/CU, 16 waves/CU. Tree phase: thread (s=tid>>5, b=tid&31) owns the
// level-3 subtree s; all 63 descendant products kept in registers; ONE syncthreads.
__global__ __launch_bounds__(256) void tree_kernel(
    const __hip_bfloat16* __restrict__ featsbf,
    const __hip_bfloat16* __restrict__ nWbf,
    const float* __restrict__ nodeb,
    float* __restrict__ out /* [16][511][8192] */) {
  __shared__ float dec_s[INTERNAL * 32];  // sigmoid decisions, heap-indexed

  const int t = blockIdx.y;
  const int b0 = blockIdx.x * 32;
  const int tid = threadIdx.x;
  const int wave = tid >> 6;
  const int lane = tid & 63;
  const int lo = lane & 15;
  const int q = lane >> 4;

  const short* Fp = (const short*)featsbf;
  const short* Np = (const short*)nWbf;

  // B frags (feats tile): 2 n-tiles x 4 k-steps, reused across all m-tiles
  short8 bfr[2][4];
#pragma unroll
  for (int nt = 0; nt < 2; nt++)
#pragma unroll
    for (int ks = 0; ks < 4; ks++)
      bfr[nt][ks] =
          *(const short8*)(Fp + (size_t)(b0 + nt * 16 + lo) * HID + ks * 32 + q * 8);

#pragma unroll
  for (int mt = 0; mt < 4; mt++) {
    const int ibase = wave * 64 + mt * 16;
    floatx4 acc0 = {0.f, 0.f, 0.f, 0.f};
    floatx4 acc1 = {0.f, 0.f, 0.f, 0.f};
#pragma unroll
    for (int ks = 0; ks < 4; ks++) {
      short8 a = *(const short8*)(Np + (size_t)(t * 256 + ibase + lo) * HID +
                                  ks * 32 + q * 8);
      acc0 = __builtin_amdgcn_mfma_f32_16x16x32_bf16(a, bfr[0][ks], acc0, 0, 0, 0);
      acc1 = __builtin_amdgcn_mfma_f32_16x16x32_bf16(a, bfr[1][ks], acc1, 0, 0, 0);
    }
#pragma unroll
    for (int r = 0; r < 4; r++) {
      const int iloc = ibase + q * 4 + r;  // D row
      if (iloc < INTERNAL) {
        const float nb = nodeb[t * INTERNAL + iloc];
        dec_s[iloc * 32 + lo]      = 1.0f / (1.0f + __expf(-(acc0[r] + nb)));
        dec_s[iloc * 32 + 16 + lo] = 1.0f / (1.0f + __expf(-(acc1[r] + nb)));
      }
    }
  }
  __syncthreads();

  const int s = tid >> 5;  // subtree id 0..7 (level-3 node)
  const int b = tid & 31;
  float* outT = out + (size_t)t * TOTAL * BATCH + b0 + b;

  // Path to level-3 node s (heap 7+s). Left child of p multiplies d(p), right 1-d(p).
  const float d0 = dec_s[0 * 32 + b];
  const float p1 = (s & 4) ? (1.0f - d0) : d0;                 // level-1 node s>>2
  const float d1 = dec_s[(1 + (s >> 2)) * 32 + b];
  const float p2 = p1 * ((s & 2) ? (1.0f - d1) : d1);          // level-2 node s>>1
  const float d2 = dec_s[(3 + (s >> 1)) * 32 + b];
  const float p3 = p2 * ((s & 1) ? (1.0f - d2) : d2);          // level-3 node s

  if (s == 0) __builtin_nontemporal_store(1.0f, outT);                       // root
  if ((s & 3) == 0)
    __builtin_nontemporal_store(p1, outT + (size_t)(1 + (s >> 2)) * BATCH);  // lvl 1
  if ((s & 1) == 0)
    __builtin_nontemporal_store(p2, outT + (size_t)(3 + (s >> 1)) * BATCH);  // lvl 2
  __builtin_nontemporal_store(p3, outT + (size_t)(7 + s) * BATCH);           // lvl 3

  // Subtree BFS in registers: rel level r (abs 3+r), 2^r nodes.
  float P[32];
  P[0] = p3;
#pragma unroll
  for (int r = 1; r <= 5; r++) {
    const int W = 1 << r;
    float nP[32];
#pragma unroll
    for (int i = 0; i < 32; i++) {
      if (i < W) {
        const int jp = (s << (r - 1)) + (i >> 1);        // parent idx within level 3+r-1
        const int ph = ((1 << (2 + r)) - 1) + jp;        // parent heap index
        const float d = dec_s[ph * 32 + b];
        const float v = P[i >> 1] * ((i & 1) ? (1.0f - d) : d);
        nP[i] = v;
        const int ch = ((1 << (3 + r)) - 1) + (s << r) + i;  // child heap index
        __builtin_nontemporal_store(v, outT + (size_t)ch * BATCH);
      }
    }
#pragma unroll
    for (int i = 0; i < 32; i++)
      if (i < W) P[i] = nP[i];
  }
}

extern "C" void kernel_launch(void* const* d_in, const int* in_sizes, int n_in,
                              void* d_out, int out_size, void* d_ws, size_t ws_size,
                              hipStream_t stream) {
  const float* X = (const float*)d_in[0];
  const float* W1 = (const float*)d_in[1];
  const float* b1 = (const float*)d_in[2];
  const float* W2 = (const float*)d_in[3];
  const float* b2 = (const float*)d_in[4];
  const float* nodeW = (const float*)d_in[5];
  const float* nodeb = (const float*)d_in[6];

  float* pred_out = (float*)d_out;
  float* results_out = pred_out + BATCH * CLS;

  char* ws = (char*)d_ws;
  __hip_bfloat16* W1T = (__hip_bfloat16*)(ws + 0);
  __hip_bfloat16* nWbf = (__hip_bfloat16*)(ws + 204800);
  __hip_bfloat16* featsbf = (__hip_bfloat16*)(ws + 1253376);

  convert_kernel<<<612, 256, 0, stream>>>(W1, nodeW, W1T, nWbf);
  feats_kernel<<<BATCH / 16, 256, 0, stream>>>(X, W1T, b1, featsbf);
  pred_kernel<<<(BATCH * CLS + 255) / 256, 256, 0, stream>>>(featsbf, W2, b2, pred_out);
  tree_kernel<<<dim3(BATCH / 32, ENSEMBLE), 256, 0, stream>>>(featsbf, nWbf, nodeb,
                                                              results_out);
}

// Round 3
// 334.777 us; speedup vs baseline: 1.1647x; 1.0264x over previous
//
#include <hip/hip_runtime.h>
#include <hip/hip_bf16.h>

#define BATCH 8192
#define IN_DIM 784
#define HID 128
#define CLS 10
#define ENSEMBLE 16
#define INTERNAL 255
#define TOTAL 511
#define KPAD 800  // 784 padded to multiple of 32 for MFMA K-steps

typedef __attribute__((ext_vector_type(8))) short short8;     // 8 bf16 (MFMA A/B frag)
typedef __attribute__((ext_vector_type(4))) float floatx4;    // MFMA C/D frag
typedef __attribute__((ext_vector_type(4))) _Float16 half4;   // 4 fp16 = 8 B

// ---- workspace layout (bytes) ----
// W1T_bf  : HID*KPAD*2        = 204800   @ 0
// nodeWbf : ENSEMBLE*256*HID*2= 1048576  @ 204800
// featsbf : BATCH*HID*2       = 2097152  @ 1253376

__device__ inline short f2bf(float f) {
  __hip_bfloat16 h = __float2bfloat16(f);
  return *reinterpret_cast<short*>(&h);
}

// K0: small fp32 -> bf16 conversions (W1 transpose+pad, nodeW pad)
__global__ void convert_kernel(const float* __restrict__ W1,
                               const float* __restrict__ nodeW,
                               __hip_bfloat16* __restrict__ W1T,
                               __hip_bfloat16* __restrict__ nWbf) {
  const int N2 = HID * KPAD;            // 102400
  const int N3 = ENSEMBLE * 256 * HID;  // 524288
  const int total = N2 + N3;
  for (int i = blockIdx.x * blockDim.x + threadIdx.x; i < total;
       i += gridDim.x * blockDim.x) {
    if (i < N2) {
      int c = i / KPAD, k = i - c * KPAD;
      float v = (k < IN_DIM) ? W1[k * HID + c] : 0.0f;  // W1T[c][k]
      W1T[i] = __float2bfloat16(v);
    } else {
      int j = i - N2;
      int t = j >> 15;
      int r = j & 32767;
      int ii = r >> 7;
      int d = r & 127;
      float v = (ii < INTERNAL) ? nodeW[(t * INTERNAL + ii) * HID + d] : 0.0f;
      nWbf[j] = __float2bfloat16(v);
    }
  }
}

// K1: featsbf = relu(X @ W1 + b1) (bf16 out) + fused prediction = feats @ W2 + b2.
// Block = 256 (4 waves) owns one 16-row m-tile; wave w owns cols [w*32, w*32+32).
__global__ __launch_bounds__(256) void feats_kernel(
    const float* __restrict__ X,
    const __hip_bfloat16* __restrict__ W1T,
    const float* __restrict__ b1,
    const float* __restrict__ W2,
    const float* __restrict__ b2,
    __hip_bfloat16* __restrict__ featsbf,
    float* __restrict__ pred_out) {
  __shared__ float feats_s[16 * HID];  // 8 KB fp32 feats tile
  __shared__ float W2s[HID * CLS];     // 5 KB
  __shared__ float b2s[CLS];

  const int tid = threadIdx.x;
  for (int i = tid; i < HID * CLS; i += 256) W2s[i] = W2[i];
  if (tid < CLS) b2s[tid] = b2[tid];

  const int wave = tid >> 6;
  const int lane = tid & 63;
  const int lo = lane & 15;
  const int q = lane >> 4;
  const int m0 = blockIdx.x * 16;
  const int cb = wave * 32;

  floatx4 acc0 = {0.f, 0.f, 0.f, 0.f};
  floatx4 acc1 = {0.f, 0.f, 0.f, 0.f};
  const short* Wp = (const short*)W1T;
  const float* Xrow = X + (size_t)(m0 + lo) * IN_DIM;

  for (int ks = 0; ks < KPAD / 32; ks++) {
    const int k0 = ks * 32 + q * 8;
    short8 a;
    if (k0 + 8 <= IN_DIM) {
      float4 x0 = *(const float4*)(Xrow + k0);
      float4 x1 = *(const float4*)(Xrow + k0 + 4);
      a[0] = f2bf(x0.x); a[1] = f2bf(x0.y); a[2] = f2bf(x0.z); a[3] = f2bf(x0.w);
      a[4] = f2bf(x1.x); a[5] = f2bf(x1.y); a[6] = f2bf(x1.z); a[7] = f2bf(x1.w);
    } else {
      a = (short8){0, 0, 0, 0, 0, 0, 0, 0};
    }
    short8 b0f = *(const short8*)(Wp + (size_t)(cb + lo) * KPAD + k0);
    short8 b1f = *(const short8*)(Wp + (size_t)(cb + 16 + lo) * KPAD + k0);
    acc0 = __builtin_amdgcn_mfma_f32_16x16x32_bf16(a, b0f, acc0, 0, 0, 0);
    acc1 = __builtin_amdgcn_mfma_f32_16x16x32_bf16(a, b1f, acc1, 0, 0, 0);
  }
#pragma unroll
  for (int nt = 0; nt < 2; nt++) {
    const floatx4 acc = nt ? acc1 : acc0;
    const int c = cb + nt * 16 + lo;  // D col = lane&15
    const float bias = b1[c];
#pragma unroll
    for (int r = 0; r < 4; r++) {
      const int rl = q * 4 + r;  // local row = quad*4 + reg
      float v = fmaxf(acc[r] + bias, 0.0f);
      featsbf[(size_t)(m0 + rl) * HID + c] = __float2bfloat16(v);
      feats_s[rl * HID + c] = v;
    }
  }
  __syncthreads();

  // fused prediction: 160 threads, thread = (row, cls)
  if (tid < 16 * CLS) {
    const int r = tid / CLS, c = tid - r * CLS;
    float acc = b2s[c];
    const float* fr = feats_s + r * HID;
#pragma unroll 8
    for (int k = 0; k < HID; k++) acc += fr[k] * W2s[k * CLS + c];
    pred_out[(size_t)(m0 + r) * CLS + c] = acc;
  }
}

// K3: fused dec-GEMM (bf16 MFMA) + sigmoid (fp16 LDS) + tree path products.
// Block = 256 (4 waves) = (tree t, 64-batch tile). LDS 32.6 KB -> 4 blocks/CU.
// GEMM: M=256 nodes x N=64 batch x K=128; wave w owns node rows [w*64, w*64+64).
// Tree: thread (s4=tid>>4, bq=tid&15) owns level-4 subtree s4 for batch quad bq
// -> every store is a 16B nontemporal float4 (256 B contiguous per 16-lane group).
__global__ __launch_bounds__(256) void tree_kernel(
    const __hip_bfloat16* __restrict__ featsbf,
    const __hip_bfloat16* __restrict__ nWbf,
    const float* __restrict__ nodeb,
    float* __restrict__ out /* [16][511][8192] */) {
  __shared__ _Float16 dec_s[INTERNAL * 64];  // heap-node-major, 64 batch

  const int t = blockIdx.y;
  const int b0 = blockIdx.x * 64;
  const int tid = threadIdx.x;
  const int wave = tid >> 6;
  const int lane = tid & 63;
  const int lo = lane & 15;
  const int q = lane >> 4;

  const short* Fp = (const short*)featsbf;
  const short* Np = (const short*)nWbf;

  // B frags (feats tile): 4 n-tiles x 4 k-steps, reused across all m-tiles
  short8 bfr[4][4];
#pragma unroll
  for (int nt = 0; nt < 4; nt++)
#pragma unroll
    for (int ks = 0; ks < 4; ks++)
      bfr[nt][ks] =
          *(const short8*)(Fp + (size_t)(b0 + nt * 16 + lo) * HID + ks * 32 + q * 8);

#pragma unroll
  for (int mt = 0; mt < 4; mt++) {
    const int ibase = wave * 64 + mt * 16;
    floatx4 acc[4];
#pragma unroll
    for (int nt = 0; nt < 4; nt++) acc[nt] = (floatx4){0.f, 0.f, 0.f, 0.f};
#pragma unroll
    for (int ks = 0; ks < 4; ks++) {
      short8 a = *(const short8*)(Np + (size_t)(t * 256 + ibase + lo) * HID +
                                  ks * 32 + q * 8);
#pragma unroll
      for (int nt = 0; nt < 4; nt++)
        acc[nt] = __builtin_amdgcn_mfma_f32_16x16x32_bf16(a, bfr[nt][ks], acc[nt], 0, 0, 0);
    }
#pragma unroll
    for (int r = 0; r < 4; r++) {
      const int iloc = ibase + q * 4 + r;  // D row
      if (iloc < INTERNAL) {
        const float nb = nodeb[t * INTERNAL + iloc];
#pragma unroll
        for (int nt = 0; nt < 4; nt++) {
          const float sig = 1.0f / (1.0f + __expf(-(acc[nt][r] + nb)));
          dec_s[iloc * 64 + nt * 16 + lo] = (_Float16)sig;
        }
      }
    }
  }
  __syncthreads();

  const int s4 = tid >> 4;  // level-4 subtree 0..15
  const int bq = tid & 15;  // batch quad (4 elems)
  float* outT = out + (size_t)t * TOTAL * BATCH + b0 + bq * 4;

#define LOAD4(node)                                              \
  ({                                                             \
    half4 _h = *(const half4*)(dec_s + (node) * 64 + bq * 4);    \
    (floatx4){(float)_h[0], (float)_h[1], (float)_h[2], (float)_h[3]}; \
  })
#define NTS(node, v) \
  __builtin_nontemporal_store((v), (floatx4*)(outT + (size_t)(node) * BATCH))

  // Path to level-4 node s4 (heap 15+s4). Left child multiplies d, right 1-d.
  floatx4 d, p;
  d = LOAD4(0);
  p = (s4 & 8) ? (1.0f - d) : d;
  if (s4 == 0) NTS(0, ((floatx4){1.f, 1.f, 1.f, 1.f}));
  if ((s4 & 7) == 0) NTS(1 + (s4 >> 3), p);
  d = LOAD4(1 + (s4 >> 3));
  p = p * ((s4 & 4) ? (1.0f - d) : d);
  if ((s4 & 3) == 0) NTS(3 + (s4 >> 2), p);
  d = LOAD4(3 + (s4 >> 2));
  p = p * ((s4 & 2) ? (1.0f - d) : d);
  if ((s4 & 1) == 0) NTS(7 + (s4 >> 1), p);
  d = LOAD4(7 + (s4 >> 1));
  p = p * ((s4 & 1) ? (1.0f - d) : d);
  NTS(15 + s4, p);

  // Subtree BFS in registers; parents at rel level r-1, children 2^r wide.
  floatx4 P[8];
  P[0] = p;
  // r=1: parent heap 15+s4, children 31 + 2*s4 + i
  {
    floatx4 dv = LOAD4(15 + s4);
    floatx4 c0 = P[0] * dv, c1 = P[0] * (1.0f - dv);
    NTS(31 + 2 * s4 + 0, c0);
    NTS(31 + 2 * s4 + 1, c1);
    P[0] = c0; P[1] = c1;
  }
  // r=2: parents 31+2*s4+ip, children 63 + 4*s4 + i
  {
    floatx4 C[4];
#pragma unroll
    for (int ip = 0; ip < 2; ip++) {
      floatx4 dv = LOAD4(31 + 2 * s4 + ip);
      C[2 * ip] = P[ip] * dv;
      C[2 * ip + 1] = P[ip] * (1.0f - dv);
      NTS(63 + 4 * s4 + 2 * ip + 0, C[2 * ip]);
      NTS(63 + 4 * s4 + 2 * ip + 1, C[2 * ip + 1]);
    }
#pragma unroll
    for (int i = 0; i < 4; i++) P[i] = C[i];
  }
  // r=3: parents 63+4*s4+ip, children 127 + 8*s4 + i
  {
    floatx4 C[8];
#pragma unroll
    for (int ip = 0; ip < 4; ip++) {
      floatx4 dv = LOAD4(63 + 4 * s4 + ip);
      C[2 * ip] = P[ip] * dv;
      C[2 * ip + 1] = P[ip] * (1.0f - dv);
      NTS(127 + 8 * s4 + 2 * ip + 0, C[2 * ip]);
      NTS(127 + 8 * s4 + 2 * ip + 1, C[2 * ip + 1]);
    }
#pragma unroll
    for (int i = 0; i < 8; i++) P[i] = C[i];
  }
  // r=4 (leaves): parents 127+8*s4+ip, children 255 + 16*s4 + i; store only
  {
#pragma unroll
    for (int ip = 0; ip < 8; ip++) {
      floatx4 dv = LOAD4(127 + 8 * s4 + ip);
      NTS(255 + 16 * s4 + 2 * ip + 0, P[ip] * dv);
      NTS(255 + 16 * s4 + 2 * ip + 1, P[ip] * (1.0f - dv));
    }
  }
#undef LOAD4
#undef NTS
}

extern "C" void kernel_launch(void* const* d_in, const int* in_sizes, int n_in,
                              void* d_out, int out_size, void* d_ws, size_t ws_size,
                              hipStream_t stream) {
  const float* X = (const float*)d_in[0];
  const float* W1 = (const float*)d_in[1];
  const float* b1 = (const float*)d_in[2];
  const float* W2 = (const float*)d_in[3];
  const float* b2 = (const float*)d_in[4];
  const float* nodeW = (const float*)d_in[5];
  const float* nodeb = (const float*)d_in[6];

  float* pred_out = (float*)d_out;
  float* results_out = pred_out + BATCH * CLS;

  char* ws = (char*)d_ws;
  __hip_bfloat16* W1T = (__hip_bfloat16*)(ws + 0);
  __hip_bfloat16* nWbf = (__hip_bfloat16*)(ws + 204800);
  __hip_bfloat16* featsbf = (__hip_bfloat16*)(ws + 1253376);

  convert_kernel<<<612, 256, 0, stream>>>(W1, nodeW, W1T, nWbf);
  feats_kernel<<<BATCH / 16, 256, 0, stream>>>(X, W1T, b1, W2, b2, featsbf, pred_out);
  tree_kernel<<<dim3(BATCH / 64, ENSEMBLE), 256, 0, stream>>>(featsbf, nWbf, nodeb,
                                                              results_out);
}